// Round 1
// 10317.518 us; speedup vs baseline: 1.4406x; 1.4406x over previous
//
#include <hip/hip_runtime.h>
#include <stdint.h>

// GRU encoder: B=64 T=512 U=E=1024 V=32000, gates z|r|h, reset_after=True.
// Round-7 structure:
//   Phase 0: init_h  — split hidden -> bf16 hi/lo planes, zero barrier counter.
//   Phase 1: gemm_xp — unchanged proven kernel: xp int16 @2^17.
//   Phase 2: gru_scan — ONE persistent kernel, 128 WGs x 512 thr, all 512
//            steps inside. Wh split ONCE into register-resident MFMA frags
//            (64 VGPR/wave, wave = K-segment of 128). h redistributed between
//            steps via global bf16 hi/lo planes; hp carried in-register.
//            Grid sync = manual monotonic-counter barrier with agent-scope
//            release/acquire fences (NO cooperative launch — that failed
//            silently in r2-r5). 128 WGs <= 256 CUs -> residency guaranteed;
//            spin budget bails visibly instead of hanging.
// ws: xp 201.33MB | h hi/lo planes 2x2x128KB | counter = 201.85MB total.

#define B_SZ   64
#define T_LEN  512
#define U_DIM  1024
#define E_DIM  1024
#define G3     3072
#define BU     (B_SZ * U_DIM)
#define XP_SCALE 131072.0f
#define XP_INV   (1.0f / 131072.0f)
#define LDT    40   // gemm LDS row stride (ushorts): 80B, 16B-aligned
#define NWG    128

typedef unsigned short ushort_t;
typedef __attribute__((ext_vector_type(8))) short bf16x8;
typedef __attribute__((ext_vector_type(4))) float f32x4;

__device__ __forceinline__ ushort_t f2bf(float f) {
  unsigned u = __builtin_bit_cast(unsigned, f);
  u += 0x7fffu + ((u >> 16) & 1u);          // RNE
  return (ushort_t)(u >> 16);
}
__device__ __forceinline__ float bf2f(ushort_t h) {
  return __builtin_bit_cast(float, (unsigned)h << 16);
}

// ---------------- Phase 1: gathered GEMM, 128x128 tile, BK=32, 4 waves,
// split-bf16, 41KB pure-static LDS (unchanged proven kernel).
__global__ __launch_bounds__(256) void gemm_xp(
    const float* __restrict__ emb,    // [V][1024] f32 (gathered rows)
    const float* __restrict__ Wx,     // [1024][3072] f32
    const int* __restrict__ x,        // [B*T] (m = b*T+t)
    const float* __restrict__ b_i,    // [3072]
    short* __restrict__ xp)           // [T][B][3072] int16 (x 2^17)
{
  __shared__ ushort_t aH[128 * LDT];
  __shared__ ushort_t aL[128 * LDT];
  __shared__ ushort_t bH[128 * LDT];
  __shared__ ushort_t bL[128 * LDT];
  const int tid = threadIdx.x, lane = tid & 63, w = tid >> 6;
  const int bx = blockIdx.x;
  const int nIdx = bx % 24, mIdx = bx / 24;
  const int m0 = mIdx * 128, n0 = nIdx * 128;

  const int aRow0 = tid >> 2, aRow1 = (tid + 256) >> 2, aKoct = tid & 3;
  const size_t aBase0 = (size_t)x[m0 + aRow0] * E_DIM + (size_t)aKoct * 8;
  const size_t aBase1 = (size_t)x[m0 + aRow1] * E_DIM + (size_t)aKoct * 8;
  const int bN = tid & 127, bKoct0 = tid >> 7;

  const int wr = (w >> 1) * 64, wc = (w & 1) * 64;
  f32x4 acc[4][4];
#pragma unroll
  for (int i = 0; i < 4; i++)
#pragma unroll
    for (int j = 0; j < 4; j++) acc[i][j] = (f32x4){0.f, 0.f, 0.f, 0.f};

  for (int k0 = 0; k0 < E_DIM; k0 += 32) {
    __syncthreads();
#pragma unroll
    for (int pp = 0; pp < 2; ++pp) {
      const float* src = emb + (pp ? aBase1 : aBase0) + k0;
      int row = pp ? aRow1 : aRow0;
      float4 v0 = *(const float4*)(src);
      float4 v1 = *(const float4*)(src + 4);
      float vv[8] = {v0.x, v0.y, v0.z, v0.w, v1.x, v1.y, v1.z, v1.w};
      bf16x8 oh, ol;
#pragma unroll
      for (int j = 0; j < 8; ++j) {
        ushort_t hi = f2bf(vv[j]);
        oh[j] = (short)hi;
        ol[j] = (short)f2bf(vv[j] - bf2f(hi));
      }
      int off = row * LDT + aKoct * 8;
      *(bf16x8*)&aH[off] = oh;
      *(bf16x8*)&aL[off] = ol;
    }
#pragma unroll
    for (int kk = 0; kk < 2; ++kk) {
      int koct = bKoct0 + 2 * kk;
      float vv[8];
#pragma unroll
      for (int e = 0; e < 8; ++e)
        vv[e] = Wx[(size_t)(k0 + koct * 8 + e) * G3 + n0 + bN];
      bf16x8 oh, ol;
#pragma unroll
      for (int j = 0; j < 8; ++j) {
        ushort_t hi = f2bf(vv[j]);
        oh[j] = (short)hi;
        ol[j] = (short)f2bf(vv[j] - bf2f(hi));
      }
      int off = bN * LDT + koct * 8;
      *(bf16x8*)&bH[off] = oh;
      *(bf16x8*)&bL[off] = ol;
    }
    __syncthreads();
    bf16x8 afH[4], afL[4], bfH[4], bfL[4];
#pragma unroll
    for (int mi = 0; mi < 4; mi++) {
      int off = (wr + mi * 16 + (lane & 15)) * LDT + (lane >> 4) * 8;
      afH[mi] = *(const bf16x8*)&aH[off];
      afL[mi] = *(const bf16x8*)&aL[off];
    }
#pragma unroll
    for (int ni = 0; ni < 4; ni++) {
      int off = (wc + ni * 16 + (lane & 15)) * LDT + (lane >> 4) * 8;
      bfH[ni] = *(const bf16x8*)&bH[off];
      bfL[ni] = *(const bf16x8*)&bL[off];
    }
#pragma unroll
    for (int mi = 0; mi < 4; mi++)
#pragma unroll
      for (int ni = 0; ni < 4; ni++) {
        acc[mi][ni] = __builtin_amdgcn_mfma_f32_16x16x32_bf16(afH[mi], bfH[ni], acc[mi][ni], 0, 0, 0);
        acc[mi][ni] = __builtin_amdgcn_mfma_f32_16x16x32_bf16(afH[mi], bfL[ni], acc[mi][ni], 0, 0, 0);
        acc[mi][ni] = __builtin_amdgcn_mfma_f32_16x16x32_bf16(afL[mi], bfH[ni], acc[mi][ni], 0, 0, 0);
      }
  }
#pragma unroll
  for (int ni = 0; ni < 4; ni++) {
    int col = n0 + wc + ni * 16 + (lane & 15);
    float bias = b_i[col];
#pragma unroll
    for (int mi = 0; mi < 4; mi++) {
      int rbase = m0 + wr + mi * 16 + (lane >> 4) * 4;
#pragma unroll
      for (int i = 0; i < 4; i++) {
        int m = rbase + i;
        int b = m >> 9, t = m & 511;
        float v = acc[mi][ni][i] + bias;
        int q = __float2int_rn(v * XP_SCALE);
        q = q > 32767 ? 32767 : (q < -32768 ? -32768 : q);
        xp[(size_t)(t * 64 + b) * G3 + col] = (short)q;
      }
    }
  }
}

// ---------------- Phase 0: split hidden -> bf16 hi/lo planes (buffer 0),
// zero the grid-barrier counter. Runs every launch (counter must reset).
__global__ __launch_bounds__(256) void init_h(
    const float* __restrict__ hidden,
    ushort_t* __restrict__ hHI, ushort_t* __restrict__ hLO,
    unsigned* __restrict__ cnt)
{
  const int i = blockIdx.x * 256 + threadIdx.x;
  if (i == 0) *cnt = 0u;
  if (i < BU) {
    const float v = hidden[i];
    const ushort_t hi = f2bf(v);
    hHI[i] = hi;
    hLO[i] = f2bf(v - bf2f(hi));
  }
}

// ---------------- Phase 2: persistent GRU scan.
// 128 WGs x 512 thr. WG owns u-block [u0,u0+8) -> 24 gate-cols as two 16-wide
// N-tiles (tile0 = z0-7|r0-7, tile1 = h0-7 + 8 zero-pad cols).
// Wave w (0..7) owns K-segment [128w,128w+128); Wh frags (hi+lo bf16, exact
// verified 16x16x32 layout: A row=lane&15 k=(lane>>4)*8+j; B col=lane&15 same
// k; C row=(lane>>4)*4+i col=lane&15) live in 64 VGPRs for all 512 steps.
// h between steps: global bf16 hi/lo planes (double-buffered); hp in-register.
// K-seg partials reduced through 64KB LDS; fused epilogue; manual grid barrier.
__global__ __launch_bounds__(512) void gru_scan(
    const float* __restrict__ hidden,  // [64][1024] f32 (hp init)
    const float* __restrict__ Wh,      // [1024][3072] f32
    const float* __restrict__ b_r,     // [3072]
    const short* __restrict__ xp,      // [T][64][3072] int16
    const int* __restrict__ x,         // [64][512]
    ushort_t* __restrict__ hHI,        // [2][64][1024] bf16 hi planes
    ushort_t* __restrict__ hLO,        // [2][64][1024] bf16 lo planes
    unsigned* __restrict__ cnt,        // barrier counter (monotonic)
    float* __restrict__ out)           // [64][512][1024] + [64][1024] state
{
  __shared__ float part[8][4][2][16][16];   // [kseg][mi][ni][row][col] 64KB
  const int tid  = threadIdx.x;
  const int lane = tid & 63;
  const int w    = tid >> 6;            // wave id = K-segment
  const int u0   = (int)blockIdx.x * 8;
  const int c16  = lane & 15;           // fragment row/col-within-tile
  const int kg   = lane >> 4;           // k-group (x8)

  // ---- Wh fragments resident in registers (built once) ----
  bf16x8 BH[4][2], BL[4][2];
#pragma unroll
  for (int ks = 0; ks < 4; ++ks)
#pragma unroll
    for (int ni = 0; ni < 2; ++ni) {
      bf16x8 bh, bl;
      const int c = ni * 16 + c16;           // local gate-col 0..31
      const int g = c >> 3, du = c & 7;      // gate 0=z 1=r 2=h
      const bool valid = (c < 24);
#pragma unroll
      for (int j = 0; j < 8; ++j) {
        float v = 0.f;
        if (valid) {
          int k = w * 128 + ks * 32 + kg * 8 + j;
          v = Wh[(size_t)k * G3 + g * 1024 + u0 + du];
        }
        ushort_t hi = f2bf(v);
        bh[j] = (short)hi;
        bl[j] = (short)f2bf(v - bf2f(hi));
      }
      BH[ks][ni] = bh;
      BL[ks][ni] = bl;
    }

  // ---- per-thread epilogue state: thread owns (b,u) = (tid>>3, u0+(tid&7))
  const int eb = tid >> 3, edu = tid & 7, eu = u0 + edu;
  const int emi = eb >> 4, erow = eb & 15;
  const float brz = b_r[eu], brr = b_r[1024 + eu], brh = b_r[2048 + eu];
  float hp = hidden[(size_t)eb * U_DIM + eu];

  unsigned target = 0;
  unsigned spins = 0;            // global spin budget: deadlock bails visibly
  for (int t = 0; t < T_LEN; ++t) {
    const ushort_t* __restrict__ rH = hHI + (size_t)(t & 1) * BU;
    const ushort_t* __restrict__ rL = hLO + (size_t)(t & 1) * BU;
    ushort_t* __restrict__ wrH = hHI + (size_t)((t + 1) & 1) * BU;
    ushort_t* __restrict__ wrL = hLO + (size_t)((t + 1) & 1) * BU;

    // epilogue operand loads: independent of h -> issue at step top,
    // latency hidden under A-loads + MFMA.
    const short* xpt = xp + ((size_t)t * B_SZ + eb) * G3 + eu;
    const short xq0 = xpt[0];
    const short xq1 = xpt[1024];
    const short xq2 = xpt[2048];
    const int   xtok = x[eb * T_LEN + t];

    // ---- A fragments: h rows, this wave's K-segment (all issued upfront) ----
    bf16x8 AH[4][4], AL[4][4];           // [ks][mi]
#pragma unroll
    for (int ks = 0; ks < 4; ++ks) {
      const int k = w * 128 + ks * 32 + kg * 8;
#pragma unroll
      for (int mi = 0; mi < 4; ++mi) {
        const size_t off = (size_t)(mi * 16 + c16) * U_DIM + k;
        AH[ks][mi] = *(const bf16x8*)(rH + off);
        AL[ks][mi] = *(const bf16x8*)(rL + off);
      }
    }

    f32x4 acc[4][2];
#pragma unroll
    for (int mi = 0; mi < 4; ++mi)
#pragma unroll
      for (int ni = 0; ni < 2; ++ni) acc[mi][ni] = (f32x4){0.f, 0.f, 0.f, 0.f};

#pragma unroll
    for (int ks = 0; ks < 4; ++ks)
#pragma unroll
      for (int mi = 0; mi < 4; ++mi) {
        const bf16x8 ah = AH[ks][mi], al = AL[ks][mi];
#pragma unroll
        for (int ni = 0; ni < 2; ++ni) {
          acc[mi][ni] = __builtin_amdgcn_mfma_f32_16x16x32_bf16(ah, BH[ks][ni], acc[mi][ni], 0, 0, 0);
          acc[mi][ni] = __builtin_amdgcn_mfma_f32_16x16x32_bf16(ah, BL[ks][ni], acc[mi][ni], 0, 0, 0);
          acc[mi][ni] = __builtin_amdgcn_mfma_f32_16x16x32_bf16(al, BH[ks][ni], acc[mi][ni], 0, 0, 0);
        }
      }

    // ---- K-segment partials -> LDS (C layout: row=(lane>>4)*4+i, col=lane&15)
#pragma unroll
    for (int mi = 0; mi < 4; ++mi)
#pragma unroll
      for (int ni = 0; ni < 2; ++ni)
#pragma unroll
        for (int i = 0; i < 4; ++i)
          part[w][mi][ni][kg * 4 + i][c16] = acc[mi][ni][i];

    __syncthreads();

    float sz = 0.f, sr = 0.f, sh = 0.f;
#pragma unroll
    for (int s = 0; s < 8; ++s) {
      sz += part[s][emi][0][erow][edu];
      sr += part[s][emi][0][erow][8 + edu];
      sh += part[s][emi][1][erow][edu];
    }

    // ---- fused gate epilogue ----
    const float hz = sz + brz, hr = sr + brr, hhv = sh + brh;
    const float xz = (float)xq0 * XP_INV;
    const float xr = (float)xq1 * XP_INV;
    const float xh = (float)xq2 * XP_INV;
    const float z = 1.f / (1.f + __expf(-(xz + hz)));
    const float r = 1.f / (1.f + __expf(-(xr + hr)));
    const float ca = xh + r * hhv;
    const float cand = 1.f - 2.f / (__expf(2.f * ca) + 1.f);   // tanh
    float hn = z * hp + (1.f - z) * cand;
    hn = (xtok != 0) ? hn : hp;

    out[((size_t)eb * T_LEN + t) * U_DIM + eu] = hn;
    const ushort_t hi = f2bf(hn);
    wrH[(size_t)eb * U_DIM + eu] = hi;
    wrL[(size_t)eb * U_DIM + eu] = f2bf(hn - bf2f(hi));
    if (t == T_LEN - 1)
      out[(size_t)B_SZ * T_LEN * U_DIM + (size_t)eb * U_DIM + eu] = hn;
    hp = hn;

    // ---- grid barrier (manual, agent-scope) ----
    // __syncthreads drains vmcnt per-wave -> all WG stores are in L2.
    // wave0: release fence (wbl2 -> MALL), arrive, spin, acquire (inv L1/L2).
    target += NWG;
    __syncthreads();
    if (w == 0) {
      __builtin_amdgcn_fence(__ATOMIC_RELEASE, "agent");
      if (lane == 0)
        __hip_atomic_fetch_add(cnt, 1u, __ATOMIC_RELAXED, __HIP_MEMORY_SCOPE_AGENT);
      while (__hip_atomic_load(cnt, __ATOMIC_RELAXED, __HIP_MEMORY_SCOPE_AGENT) < target) {
        __builtin_amdgcn_s_sleep(1);
        if (++spins > (1u << 22)) break;   // fail visibly, don't hang
      }
      __builtin_amdgcn_fence(__ATOMIC_ACQUIRE, "agent");
    }
    __syncthreads();
  }
}

// ---------------- launch
extern "C" void kernel_launch(void* const* d_in, const int* in_sizes, int n_in,
                              void* d_out, int out_size, void* d_ws, size_t ws_size,
                              hipStream_t stream) {
  const int*   x      = (const int*)  d_in[0];
  const float* hidden = (const float*)d_in[1];
  const float* emb    = (const float*)d_in[2];
  const float* Wx     = (const float*)d_in[3];
  const float* Wh     = (const float*)d_in[4];
  const float* b_i    = (const float*)d_in[5];
  const float* b_r    = (const float*)d_in[6];
  float* out = (float*)d_out;

  const size_t XP_B = (size_t)T_LEN * B_SZ * G3 * 2;   // 201,326,592 (int16)
  const size_t NEED = XP_B + 8 * (size_t)BU + 256;     // + h planes + counter
  if (ws_size < NEED) return;

  short*    xp  = (short*)d_ws;
  ushort_t* hHI = (ushort_t*)((char*)d_ws + XP_B);     // [2][BU] bf16-hi
  ushort_t* hLO = hHI + 2 * (size_t)BU;                // [2][BU] bf16-lo
  unsigned* cnt = (unsigned*)(hLO + 2 * (size_t)BU);

  init_h<<<BU / 256, 256, 0, stream>>>(hidden, hHI, hLO, cnt);
  gemm_xp<<<(32768 / 128) * (G3 / 128), 256, 0, stream>>>(emb, Wx, x, b_i, xp);
  gru_scan<<<NWG, 512, 0, stream>>>(hidden, Wh, b_r, xp, x, hHI, hLO, cnt, out);
}

// Round 2
// 7847.776 us; speedup vs baseline: 1.8939x; 1.3147x over previous
//
#include <hip/hip_runtime.h>
#include <stdint.h>

// GRU encoder: B=64 T=512 U=E=1024 V=32000, gates z|r|h, reset_after=True.
// Round-8 structure:
//   Phase 0: init_h  — split hidden -> bf16 hi/lo planes, zero barrier counter.
//   Phase 1: gemm_xp — unchanged proven kernel: xp int16 @2^17.
//   Phase 2: gru_scan — ONE persistent kernel, 128 WGs x 512 thr.
//     r7 lesson (rocprof): 18.5us/step, MfmaUtil 3.5% -> latency-bound on
//     (a) per-step agent fences (buffer_wbl2/inv = full L2 walk, 2x/step),
//     (b) compiler-serialized A-loads (VGPR=84 proved loads sunk to uses),
//     (c) 4-way LDS bank conflicts on part writes (5.9e7 cycles).
//     r8: NO fences. h exchange via sc0+sc1 (MALL-coherent) inline-asm
//     loads/stores; barrier = vmcnt drain + relaxed agent atomic + sc1 spin.
//     All loop vmem is ordered volatile asm -> counted s_waitcnt vmcnt(N)
//     software pipeline (2-deep ks-group prefetch). part -> [col][row]
//     layout, ds_write_b128 (conflict-free writes). xp prefetch under barrier.
// ws: xp 201.33MB | h hi/lo planes 2x2x128KB | counter = 201.85MB total.

#define B_SZ   64
#define T_LEN  512
#define U_DIM  1024
#define E_DIM  1024
#define G3     3072
#define BU     (B_SZ * U_DIM)
#define XP_SCALE 131072.0f
#define XP_INV   (1.0f / 131072.0f)
#define LDT    40   // gemm LDS row stride (ushorts): 80B, 16B-aligned
#define NWG    128

typedef unsigned short ushort_t;
typedef __attribute__((ext_vector_type(8))) short bf16x8;
typedef __attribute__((ext_vector_type(4))) float f32x4;

__device__ __forceinline__ ushort_t f2bf(float f) {
  unsigned u = __builtin_bit_cast(unsigned, f);
  u += 0x7fffu + ((u >> 16) & 1u);          // RNE
  return (ushort_t)(u >> 16);
}
__device__ __forceinline__ float bf2f(ushort_t h) {
  return __builtin_bit_cast(float, (unsigned)h << 16);
}

// ---- coherent (MALL-point) memory ops: bypass L1+L2 via sc0 sc1 ----
__device__ __forceinline__ bf16x8 ldg_cohere_b128(const ushort_t* p) {
  bf16x8 r;
  asm volatile("global_load_dwordx4 %0, %1, off sc0 sc1"
               : "=v"(r) : "v"(p) : "memory");
  return r;
}
__device__ __forceinline__ void stg_cohere_u16(ushort_t* p, unsigned v) {
  asm volatile("global_store_short %0, %1, off sc0 sc1"
               :: "v"(p), "v"(v) : "memory");
}
__device__ __forceinline__ unsigned ldg_cohere_u32(const unsigned* p) {
  unsigned r;
  asm volatile("global_load_dword %0, %1, off sc0 sc1\n\ts_waitcnt vmcnt(0)"
               : "=v"(r) : "v"(p) : "memory");
  return r;
}
// ---- ordinary cached loads, but as ordered volatile asm (vmcnt counting) ----
__device__ __forceinline__ int ldg_sshort(const short* p) {
  int r;
  asm volatile("global_load_sshort %0, %1, off"
               : "=v"(r) : "v"(p) : "memory");
  return r;
}
__device__ __forceinline__ int ldg_s32(const int* p) {
  int r;
  asm volatile("global_load_dword %0, %1, off"
               : "=v"(r) : "v"(p) : "memory");
  return r;
}
#define WAITV(n) do { asm volatile("s_waitcnt vmcnt(" #n ")" ::: "memory"); \
                      __builtin_amdgcn_sched_barrier(0); } while (0)

// ---------------- Phase 1: gathered GEMM, 128x128 tile, BK=32, 4 waves,
// split-bf16, 41KB pure-static LDS (unchanged proven kernel).
__global__ __launch_bounds__(256) void gemm_xp(
    const float* __restrict__ emb,    // [V][1024] f32 (gathered rows)
    const float* __restrict__ Wx,     // [1024][3072] f32
    const int* __restrict__ x,        // [B*T] (m = b*T+t)
    const float* __restrict__ b_i,    // [3072]
    short* __restrict__ xp)           // [T][B][3072] int16 (x 2^17)
{
  __shared__ ushort_t aH[128 * LDT];
  __shared__ ushort_t aL[128 * LDT];
  __shared__ ushort_t bH[128 * LDT];
  __shared__ ushort_t bL[128 * LDT];
  const int tid = threadIdx.x, lane = tid & 63, w = tid >> 6;
  const int bx = blockIdx.x;
  const int nIdx = bx % 24, mIdx = bx / 24;
  const int m0 = mIdx * 128, n0 = nIdx * 128;

  const int aRow0 = tid >> 2, aRow1 = (tid + 256) >> 2, aKoct = tid & 3;
  const size_t aBase0 = (size_t)x[m0 + aRow0] * E_DIM + (size_t)aKoct * 8;
  const size_t aBase1 = (size_t)x[m0 + aRow1] * E_DIM + (size_t)aKoct * 8;
  const int bN = tid & 127, bKoct0 = tid >> 7;

  const int wr = (w >> 1) * 64, wc = (w & 1) * 64;
  f32x4 acc[4][4];
#pragma unroll
  for (int i = 0; i < 4; i++)
#pragma unroll
    for (int j = 0; j < 4; j++) acc[i][j] = (f32x4){0.f, 0.f, 0.f, 0.f};

  for (int k0 = 0; k0 < E_DIM; k0 += 32) {
    __syncthreads();
#pragma unroll
    for (int pp = 0; pp < 2; ++pp) {
      const float* src = emb + (pp ? aBase1 : aBase0) + k0;
      int row = pp ? aRow1 : aRow0;
      float4 v0 = *(const float4*)(src);
      float4 v1 = *(const float4*)(src + 4);
      float vv[8] = {v0.x, v0.y, v0.z, v0.w, v1.x, v1.y, v1.z, v1.w};
      bf16x8 oh, ol;
#pragma unroll
      for (int j = 0; j < 8; ++j) {
        ushort_t hi = f2bf(vv[j]);
        oh[j] = (short)hi;
        ol[j] = (short)f2bf(vv[j] - bf2f(hi));
      }
      int off = row * LDT + aKoct * 8;
      *(bf16x8*)&aH[off] = oh;
      *(bf16x8*)&aL[off] = ol;
    }
#pragma unroll
    for (int kk = 0; kk < 2; ++kk) {
      int koct = bKoct0 + 2 * kk;
      float vv[8];
#pragma unroll
      for (int e = 0; e < 8; ++e)
        vv[e] = Wx[(size_t)(k0 + koct * 8 + e) * G3 + n0 + bN];
      bf16x8 oh, ol;
#pragma unroll
      for (int j = 0; j < 8; ++j) {
        ushort_t hi = f2bf(vv[j]);
        oh[j] = (short)hi;
        ol[j] = (short)f2bf(vv[j] - bf2f(hi));
      }
      int off = bN * LDT + koct * 8;
      *(bf16x8*)&bH[off] = oh;
      *(bf16x8*)&bL[off] = ol;
    }
    __syncthreads();
    bf16x8 afH[4], afL[4], bfH[4], bfL[4];
#pragma unroll
    for (int mi = 0; mi < 4; mi++) {
      int off = (wr + mi * 16 + (lane & 15)) * LDT + (lane >> 4) * 8;
      afH[mi] = *(const bf16x8*)&aH[off];
      afL[mi] = *(const bf16x8*)&aL[off];
    }
#pragma unroll
    for (int ni = 0; ni < 4; ni++) {
      int off = (wc + ni * 16 + (lane & 15)) * LDT + (lane >> 4) * 8;
      bfH[ni] = *(const bf16x8*)&bH[off];
      bfL[ni] = *(const bf16x8*)&bL[off];
    }
#pragma unroll
    for (int mi = 0; mi < 4; mi++)
#pragma unroll
      for (int ni = 0; ni < 4; ni++) {
        acc[mi][ni] = __builtin_amdgcn_mfma_f32_16x16x32_bf16(afH[mi], bfH[ni], acc[mi][ni], 0, 0, 0);
        acc[mi][ni] = __builtin_amdgcn_mfma_f32_16x16x32_bf16(afH[mi], bfL[ni], acc[mi][ni], 0, 0, 0);
        acc[mi][ni] = __builtin_amdgcn_mfma_f32_16x16x32_bf16(afL[mi], bfH[ni], acc[mi][ni], 0, 0, 0);
      }
  }
#pragma unroll
  for (int ni = 0; ni < 4; ni++) {
    int col = n0 + wc + ni * 16 + (lane & 15);
    float bias = b_i[col];
#pragma unroll
    for (int mi = 0; mi < 4; mi++) {
      int rbase = m0 + wr + mi * 16 + (lane >> 4) * 4;
#pragma unroll
      for (int i = 0; i < 4; i++) {
        int m = rbase + i;
        int b = m >> 9, t = m & 511;
        float v = acc[mi][ni][i] + bias;
        int q = __float2int_rn(v * XP_SCALE);
        q = q > 32767 ? 32767 : (q < -32768 ? -32768 : q);
        xp[(size_t)(t * 64 + b) * G3 + col] = (short)q;
      }
    }
  }
}

// ---------------- Phase 0: split hidden -> bf16 hi/lo planes (buffer 0),
// zero the grid-barrier counter. Runs every launch (counter must reset).
__global__ __launch_bounds__(256) void init_h(
    const float* __restrict__ hidden,
    ushort_t* __restrict__ hHI, ushort_t* __restrict__ hLO,
    unsigned* __restrict__ cnt)
{
  const int i = blockIdx.x * 256 + threadIdx.x;
  if (i == 0) *cnt = 0u;
  if (i < BU) {
    const float v = hidden[i];
    const ushort_t hi = f2bf(v);
    hHI[i] = hi;
    hLO[i] = f2bf(v - bf2f(hi));
  }
}

// ---------------- Phase 2: persistent GRU scan (fence-free).
// 128 WGs x 512 thr. WG owns u-block [u0,u0+8) -> 24 gate-cols as two 16-wide
// N-tiles. Wave w (0..7) owns K-segment [128w,128w+128); Wh frags (hi+lo bf16)
// resident in 64 VGPRs for all 512 steps. h exchanged via sc0+sc1 global ops
// (coherent at MALL, no cache maintenance); grid barrier = drain + atomic +
// sc1 spin. A-loads software-pipelined with counted vmcnt (all loop vmem is
// ordered volatile asm; vmem order per iter:
//   [4 xq prefetched] G0(8) G1(8) | w16? no: see WAITV counts below).
__global__ __launch_bounds__(512) void gru_scan(
    const float* __restrict__ hidden,  // [64][1024] f32 (hp init)
    const float* __restrict__ Wh,      // [1024][3072] f32
    const float* __restrict__ b_r,     // [3072]
    const short* __restrict__ xp,      // [T][64][3072] int16
    const int* __restrict__ x,         // [64][512]
    ushort_t* __restrict__ hHI,        // [2][64][1024] bf16 hi planes
    ushort_t* __restrict__ hLO,        // [2][64][1024] bf16 lo planes
    unsigned* __restrict__ cnt,        // barrier counter (monotonic)
    float* __restrict__ out)           // [64][512][1024] f32 + [64][1024] state
{
  // partials, TRANSPOSED: [kseg][mi][ni][col][row] -> f32x4 write is one
  // ds_write_b128 (rows kg*4..+3 contiguous); kills the r7 4-way conflicts.
  __shared__ float part[8][4][2][16][16];   // 64KB
  const int tid  = threadIdx.x;
  const int lane = tid & 63;
  const int w    = tid >> 6;            // wave id = K-segment
  const int u0   = (int)blockIdx.x * 8;
  const int c16  = lane & 15;           // fragment row/col-within-tile
  const int kg   = lane >> 4;           // k-group (x8)

  // ---- Wh fragments resident in registers (built once, cached loads) ----
  bf16x8 BH[4][2], BL[4][2];
#pragma unroll
  for (int ks = 0; ks < 4; ++ks)
#pragma unroll
    for (int ni = 0; ni < 2; ++ni) {
      bf16x8 bh, bl;
      const int c = ni * 16 + c16;           // local gate-col 0..31
      const int g = c >> 3, du = c & 7;      // gate 0=z 1=r 2=h
      const bool valid = (c < 24);
#pragma unroll
      for (int j = 0; j < 8; ++j) {
        float v = 0.f;
        if (valid) {
          int k = w * 128 + ks * 32 + kg * 8 + j;
          v = Wh[(size_t)k * G3 + g * 1024 + u0 + du];
        }
        ushort_t hi = f2bf(v);
        bh[j] = (short)hi;
        bl[j] = (short)f2bf(v - bf2f(hi));
      }
      BH[ks][ni] = bh;
      BL[ks][ni] = bl;
    }

  // ---- per-thread epilogue state: thread owns (b,u) = (tid>>3, u0+(tid&7))
  const int eb = tid >> 3, edu = tid & 7, eu = u0 + edu;
  const int emi = eb >> 4, erow = eb & 15;
  const float brz = b_r[eu], brr = b_r[1024 + eu], brh = b_r[2048 + eu];
  float hp = hidden[(size_t)eb * U_DIM + eu];

  // drain everything before entering the counted-vmcnt regime
  asm volatile("s_waitcnt vmcnt(0) lgkmcnt(0)" ::: "memory");

  // prologue: prefetch xq for t=0 (4 cached asm loads, outstanding at loop top)
  int xq0 = ldg_sshort(xp + (size_t)eb * G3 + eu);
  int xq1 = ldg_sshort(xp + (size_t)eb * G3 + 1024 + eu);
  int xq2 = ldg_sshort(xp + (size_t)eb * G3 + 2048 + eu);
  int xtok = ldg_s32(x + eb * T_LEN + 0);

  unsigned target = 0;
  unsigned spins = 0;            // global spin budget: deadlock bails visibly
  for (int t = 0; t < T_LEN; ++t) {
    const ushort_t* __restrict__ rH = hHI + (size_t)(t & 1) * BU;
    const ushort_t* __restrict__ rL = hLO + (size_t)(t & 1) * BU;
    ushort_t* __restrict__ wrH = hHI + (size_t)((t + 1) & 1) * BU;
    ushort_t* __restrict__ wrL = hLO + (size_t)((t + 1) & 1) * BU;

    const ushort_t* pH = rH + (size_t)c16 * U_DIM + w * 128 + kg * 8;
    const ushort_t* pL = rL + (size_t)c16 * U_DIM + w * 128 + kg * 8;

#define LDGRP(AH_, AL_, ks_) \
    _Pragma("unroll") \
    for (int mi = 0; mi < 4; ++mi) { \
      AH_[mi] = ldg_cohere_b128(pH + (size_t)mi * (16 * U_DIM) + (ks_) * 32); \
      AL_[mi] = ldg_cohere_b128(pL + (size_t)mi * (16 * U_DIM) + (ks_) * 32); \
    }
#define COMP(AH_, AL_, ks_) \
    _Pragma("unroll") \
    for (int mi = 0; mi < 4; ++mi) { \
      const bf16x8 ah = AH_[mi], al = AL_[mi]; \
      _Pragma("unroll") \
      for (int ni = 0; ni < 2; ++ni) { \
        acc[mi][ni] = __builtin_amdgcn_mfma_f32_16x16x32_bf16(ah, BH[ks_][ni], acc[mi][ni], 0, 0, 0); \
        acc[mi][ni] = __builtin_amdgcn_mfma_f32_16x16x32_bf16(ah, BL[ks_][ni], acc[mi][ni], 0, 0, 0); \
        acc[mi][ni] = __builtin_amdgcn_mfma_f32_16x16x32_bf16(al, BH[ks_][ni], acc[mi][ni], 0, 0, 0); \
      } \
    }

    f32x4 acc[4][2];
#pragma unroll
    for (int mi = 0; mi < 4; ++mi)
#pragma unroll
      for (int ni = 0; ni < 2; ++ni) acc[mi][ni] = (f32x4){0.f, 0.f, 0.f, 0.f};

    // vmem order (volatile asm, per wave): xq(4 outstanding) G0(8) G1(8)
    //   WAITV(8): xq+G0 done | G2(8) WAITV(8): G1 done | G3(8) WAITV(8): G2
    //   done | WAITV(0): G3 done.  Peak A in flight = 2 groups (64 VGPR).
    bf16x8 AH0[4], AL0[4], AH1[4], AL1[4], AH2[4], AL2[4], AH3[4], AL3[4];
    LDGRP(AH0, AL0, 0)
    LDGRP(AH1, AL1, 1)
    WAITV(8);
    COMP(AH0, AL0, 0)
    LDGRP(AH2, AL2, 2)
    WAITV(8);
    COMP(AH1, AL1, 1)
    LDGRP(AH3, AL3, 3)
    WAITV(8);
    COMP(AH2, AL2, 2)
    WAITV(0);
    COMP(AH3, AL3, 3)
#undef LDGRP
#undef COMP

    // ---- K-segment partials -> LDS, one ds_write_b128 per (mi,ni) ----
#pragma unroll
    for (int mi = 0; mi < 4; ++mi)
#pragma unroll
      for (int ni = 0; ni < 2; ++ni)
        *(f32x4*)&part[w][mi][ni][c16][kg * 4] = acc[mi][ni];

    __syncthreads();

    float sz = 0.f, sr = 0.f, sh = 0.f;
#pragma unroll
    for (int s = 0; s < 8; ++s) {
      sz += part[s][emi][0][edu][erow];
      sr += part[s][emi][0][8 + edu][erow];
      sh += part[s][emi][1][edu][erow];
    }

    // ---- fused gate epilogue (xq values prefetched last iteration) ----
    const float hz = sz + brz, hr = sr + brr, hhv = sh + brh;
    const float xz = (float)xq0 * XP_INV;
    const float xr = (float)xq1 * XP_INV;
    const float xh = (float)xq2 * XP_INV;
    const float z = 1.f / (1.f + __expf(-(xz + hz)));
    const float r = 1.f / (1.f + __expf(-(xr + hr)));
    const float ca = xh + r * hhv;
    const float cand = 1.f - 2.f / (__expf(2.f * ca) + 1.f);   // tanh
    float hn = z * hp + (1.f - z) * cand;
    hn = (xtok != 0) ? hn : hp;
    hp = hn;

    out[((size_t)eb * T_LEN + t) * U_DIM + eu] = hn;        // plain store (1)
    const ushort_t hi = f2bf(hn);
    const ushort_t lo = f2bf(hn - bf2f(hi));
    stg_cohere_u16(wrH + (size_t)eb * U_DIM + eu, (unsigned)hi);   // (2)
    stg_cohere_u16(wrL + (size_t)eb * U_DIM + eu, (unsigned)lo);   // (3)

    // prefetch next step's xq/x under the barrier (4 outstanding at loop top)
    const int tp = (t < T_LEN - 1) ? t + 1 : t;
    xq0 = ldg_sshort(xp + ((size_t)tp * B_SZ + eb) * G3 + eu);
    xq1 = ldg_sshort(xp + ((size_t)tp * B_SZ + eb) * G3 + 1024 + eu);
    xq2 = ldg_sshort(xp + ((size_t)tp * B_SZ + eb) * G3 + 2048 + eu);
    xtok = ldg_s32(x + eb * T_LEN + tp);
    WAITV(4);   // out + h stores drained (visible at MALL); xq still flying

    // ---- grid barrier (fence-free) ----
    target += NWG;
    __syncthreads();
    if (tid == 0)
      __hip_atomic_fetch_add(cnt, 1u, __ATOMIC_RELAXED, __HIP_MEMORY_SCOPE_AGENT);
    if (w == 0) {
      while (spins < (1u << 22)) {
        if (ldg_cohere_u32(cnt) >= target) break;
        __builtin_amdgcn_s_sleep(2);
        ++spins;
      }
    }
    __syncthreads();
    __builtin_amdgcn_sched_barrier(0);
  }

  // final state = hp (exact register carry)
  out[(size_t)B_SZ * T_LEN * U_DIM + (size_t)eb * U_DIM + eu] = hp;
}

// ---------------- launch
extern "C" void kernel_launch(void* const* d_in, const int* in_sizes, int n_in,
                              void* d_out, int out_size, void* d_ws, size_t ws_size,
                              hipStream_t stream) {
  const int*   x      = (const int*)  d_in[0];
  const float* hidden = (const float*)d_in[1];
  const float* emb    = (const float*)d_in[2];
  const float* Wx     = (const float*)d_in[3];
  const float* Wh     = (const float*)d_in[4];
  const float* b_i    = (const float*)d_in[5];
  const float* b_r    = (const float*)d_in[6];
  float* out = (float*)d_out;

  const size_t XP_B = (size_t)T_LEN * B_SZ * G3 * 2;   // 201,326,592 (int16)
  const size_t NEED = XP_B + 8 * (size_t)BU + 256;     // + h planes + counter
  if (ws_size < NEED) return;

  short*    xp  = (short*)d_ws;
  ushort_t* hHI = (ushort_t*)((char*)d_ws + XP_B);     // [2][BU] bf16-hi
  ushort_t* hLO = hHI + 2 * (size_t)BU;                // [2][BU] bf16-lo
  unsigned* cnt = (unsigned*)(hLO + 2 * (size_t)BU);

  init_h<<<BU / 256, 256, 0, stream>>>(hidden, hHI, hLO, cnt);
  gemm_xp<<<(32768 / 128) * (G3 / 128), 256, 0, stream>>>(emb, Wx, x, b_i, xp);
  gru_scan<<<NWG, 512, 0, stream>>>(hidden, Wh, b_r, xp, x, hHI, hLO, cnt, out);
}

// Round 3
// 3081.922 us; speedup vs baseline: 4.8226x; 2.5464x over previous
//
#include <hip/hip_runtime.h>
#include <stdint.h>

// GRU encoder: B=64 T=512 U=E=1024 V=32000, gates z|r|h, reset_after=True.
// Round-9 structure:
//   Phase 0: init_h  — split hidden -> bf16 hi/lo planes, zero 4 group counters.
//   Phase 1: gemm_xp — unchanged proven kernel: xp int16 @2^17.
//   Phase 2: gru_scan — persistent, 256 WGs x 512 thr, 2-D partition:
//     batch-group bi (4 x 16 rows) x u-tile uj (64 x 16 u). GRU recurrence is
//     independent per batch row -> WG only needs its group's 16 h-rows:
//     A-broadcast 64KB/WG (was 256KB; total 32->16MB/step), and the barrier
//     is PER-GROUP (4 independent counters of 64 WGs, separate cachelines).
//     u-tile=16 -> gates are exactly 3 unpadded 16-wide B-tiles (-25% MFMA).
//     r8 lesson: transposed part[] made LDS conflicts 3x WORSE (1.76e8) ->
//     r9 part is lane-major [kseg][gate][lane][4]: b128 writes contiguous
//     (0 conflicts), reduce reads 2-way (free). sc0/sc1 coherence + counted
//     vmcnt pipeline + xp prefetch kept exactly as r8 (HW-proven protocol).
// ws: xp 201.33MB | h hi/lo planes 2x2x128KB | counters 1KB = 201.85MB.

#define B_SZ   64
#define T_LEN  512
#define U_DIM  1024
#define E_DIM  1024
#define G3     3072
#define BU     (B_SZ * U_DIM)
#define XP_SCALE 131072.0f
#define XP_INV   (1.0f / 131072.0f)
#define LDT    40   // gemm LDS row stride (ushorts): 80B, 16B-aligned
#define NWG    256
#define GRPWG  64   // WGs per batch-group barrier

typedef unsigned short ushort_t;
typedef __attribute__((ext_vector_type(8))) short bf16x8;
typedef __attribute__((ext_vector_type(4))) float f32x4;

__device__ __forceinline__ ushort_t f2bf(float f) {
  unsigned u = __builtin_bit_cast(unsigned, f);
  u += 0x7fffu + ((u >> 16) & 1u);          // RNE
  return (ushort_t)(u >> 16);
}
__device__ __forceinline__ float bf2f(ushort_t h) {
  return __builtin_bit_cast(float, (unsigned)h << 16);
}

// ---- coherent (MALL-point) memory ops: bypass L1+L2 via sc0 sc1 ----
__device__ __forceinline__ bf16x8 ldg_cohere_b128(const ushort_t* p) {
  bf16x8 r;
  asm volatile("global_load_dwordx4 %0, %1, off sc0 sc1"
               : "=v"(r) : "v"(p) : "memory");
  return r;
}
__device__ __forceinline__ void stg_cohere_u16(ushort_t* p, unsigned v) {
  asm volatile("global_store_short %0, %1, off sc0 sc1"
               :: "v"(p), "v"(v) : "memory");
}
__device__ __forceinline__ unsigned ldg_cohere_u32(const unsigned* p) {
  unsigned r;
  asm volatile("global_load_dword %0, %1, off sc0 sc1\n\ts_waitcnt vmcnt(0)"
               : "=v"(r) : "v"(p) : "memory");
  return r;
}
// ---- ordinary cached loads, but as ordered volatile asm (vmcnt counting) ----
__device__ __forceinline__ int ldg_sshort(const short* p) {
  int r;
  asm volatile("global_load_sshort %0, %1, off"
               : "=v"(r) : "v"(p) : "memory");
  return r;
}
__device__ __forceinline__ int ldg_s32(const int* p) {
  int r;
  asm volatile("global_load_dword %0, %1, off"
               : "=v"(r) : "v"(p) : "memory");
  return r;
}
#define WAITV(n) do { asm volatile("s_waitcnt vmcnt(" #n ")" ::: "memory"); \
                      __builtin_amdgcn_sched_barrier(0); } while (0)

// ---------------- Phase 1: gathered GEMM, 128x128 tile, BK=32, 4 waves,
// split-bf16, 41KB pure-static LDS (unchanged proven kernel).
__global__ __launch_bounds__(256) void gemm_xp(
    const float* __restrict__ emb,    // [V][1024] f32 (gathered rows)
    const float* __restrict__ Wx,     // [1024][3072] f32
    const int* __restrict__ x,        // [B*T] (m = b*T+t)
    const float* __restrict__ b_i,    // [3072]
    short* __restrict__ xp)           // [T][B][3072] int16 (x 2^17)
{
  __shared__ ushort_t aH[128 * LDT];
  __shared__ ushort_t aL[128 * LDT];
  __shared__ ushort_t bH[128 * LDT];
  __shared__ ushort_t bL[128 * LDT];
  const int tid = threadIdx.x, lane = tid & 63, w = tid >> 6;
  const int bx = blockIdx.x;
  const int nIdx = bx % 24, mIdx = bx / 24;
  const int m0 = mIdx * 128, n0 = nIdx * 128;

  const int aRow0 = tid >> 2, aRow1 = (tid + 256) >> 2, aKoct = tid & 3;
  const size_t aBase0 = (size_t)x[m0 + aRow0] * E_DIM + (size_t)aKoct * 8;
  const size_t aBase1 = (size_t)x[m0 + aRow1] * E_DIM + (size_t)aKoct * 8;
  const int bN = tid & 127, bKoct0 = tid >> 7;

  const int wr = (w >> 1) * 64, wc = (w & 1) * 64;
  f32x4 acc[4][4];
#pragma unroll
  for (int i = 0; i < 4; i++)
#pragma unroll
    for (int j = 0; j < 4; j++) acc[i][j] = (f32x4){0.f, 0.f, 0.f, 0.f};

  for (int k0 = 0; k0 < E_DIM; k0 += 32) {
    __syncthreads();
#pragma unroll
    for (int pp = 0; pp < 2; ++pp) {
      const float* src = emb + (pp ? aBase1 : aBase0) + k0;
      int row = pp ? aRow1 : aRow0;
      float4 v0 = *(const float4*)(src);
      float4 v1 = *(const float4*)(src + 4);
      float vv[8] = {v0.x, v0.y, v0.z, v0.w, v1.x, v1.y, v1.z, v1.w};
      bf16x8 oh, ol;
#pragma unroll
      for (int j = 0; j < 8; ++j) {
        ushort_t hi = f2bf(vv[j]);
        oh[j] = (short)hi;
        ol[j] = (short)f2bf(vv[j] - bf2f(hi));
      }
      int off = row * LDT + aKoct * 8;
      *(bf16x8*)&aH[off] = oh;
      *(bf16x8*)&aL[off] = ol;
    }
#pragma unroll
    for (int kk = 0; kk < 2; ++kk) {
      int koct = bKoct0 + 2 * kk;
      float vv[8];
#pragma unroll
      for (int e = 0; e < 8; ++e)
        vv[e] = Wx[(size_t)(k0 + koct * 8 + e) * G3 + n0 + bN];
      bf16x8 oh, ol;
#pragma unroll
      for (int j = 0; j < 8; ++j) {
        ushort_t hi = f2bf(vv[j]);
        oh[j] = (short)hi;
        ol[j] = (short)f2bf(vv[j] - bf2f(hi));
      }
      int off = bN * LDT + koct * 8;
      *(bf16x8*)&bH[off] = oh;
      *(bf16x8*)&bL[off] = ol;
    }
    __syncthreads();
    bf16x8 afH[4], afL[4], bfH[4], bfL[4];
#pragma unroll
    for (int mi = 0; mi < 4; mi++) {
      int off = (wr + mi * 16 + (lane & 15)) * LDT + (lane >> 4) * 8;
      afH[mi] = *(const bf16x8*)&aH[off];
      afL[mi] = *(const bf16x8*)&aL[off];
    }
#pragma unroll
    for (int ni = 0; ni < 4; ni++) {
      int off = (wc + ni * 16 + (lane & 15)) * LDT + (lane >> 4) * 8;
      bfH[ni] = *(const bf16x8*)&bH[off];
      bfL[ni] = *(const bf16x8*)&bL[off];
    }
#pragma unroll
    for (int mi = 0; mi < 4; mi++)
#pragma unroll
      for (int ni = 0; ni < 4; ni++) {
        acc[mi][ni] = __builtin_amdgcn_mfma_f32_16x16x32_bf16(afH[mi], bfH[ni], acc[mi][ni], 0, 0, 0);
        acc[mi][ni] = __builtin_amdgcn_mfma_f32_16x16x32_bf16(afH[mi], bfL[ni], acc[mi][ni], 0, 0, 0);
        acc[mi][ni] = __builtin_amdgcn_mfma_f32_16x16x32_bf16(afL[mi], bfH[ni], acc[mi][ni], 0, 0, 0);
      }
  }
#pragma unroll
  for (int ni = 0; ni < 4; ni++) {
    int col = n0 + wc + ni * 16 + (lane & 15);
    float bias = b_i[col];
#pragma unroll
    for (int mi = 0; mi < 4; mi++) {
      int rbase = m0 + wr + mi * 16 + (lane >> 4) * 4;
#pragma unroll
      for (int i = 0; i < 4; i++) {
        int m = rbase + i;
        int b = m >> 9, t = m & 511;
        float v = acc[mi][ni][i] + bias;
        int q = __float2int_rn(v * XP_SCALE);
        q = q > 32767 ? 32767 : (q < -32768 ? -32768 : q);
        xp[(size_t)(t * 64 + b) * G3 + col] = (short)q;
      }
    }
  }
}

// ---------------- Phase 0: split hidden -> bf16 hi/lo planes (buffer 0),
// zero the 4 group-barrier counters (256B apart). Runs every launch.
__global__ __launch_bounds__(256) void init_h(
    const float* __restrict__ hidden,
    ushort_t* __restrict__ hHI, ushort_t* __restrict__ hLO,
    unsigned* __restrict__ cnt)
{
  const int i = blockIdx.x * 256 + threadIdx.x;
  if (blockIdx.x == 0 && threadIdx.x < 256) cnt[threadIdx.x] = 0u;
  if (i < BU) {
    const float v = hidden[i];
    const ushort_t hi = f2bf(v);
    hHI[i] = hi;
    hLO[i] = f2bf(v - bf2f(hi));
  }
}

// ---------------- Phase 2: persistent GRU scan, 2-D partition.
// WG(bx): uj = bx&63 (u-tile of 16), bi = bx>>6 (batch-group of 16 rows).
// Wave w (0..7) owns K-segment [128w,128w+128). B-frags: [ks][gate], gate is
// the ni tile directly (u-tile 16 -> no padding). Verified MFMA layouts:
// A row=lane&15 k=(lane>>4)*8+j; B col=lane&15 same k; C row=(lane>>4)*4+i
// col=lane&15. 16 h-rows/WG -> A = 8 b128 loads/wave/step (sc0 sc1, MALL).
// Per-group barrier: counter bi, 64 arrivals. part[] lane-major: b128 writes
// contiguous (0 bank conflicts), reduce reads 2-way (free).
__global__ __launch_bounds__(512) void gru_scan(
    const float* __restrict__ hidden,  // [64][1024] f32 (hp init)
    const float* __restrict__ Wh,      // [1024][3072] f32
    const float* __restrict__ b_r,     // [3072]
    const short* __restrict__ xp,      // [T][64][3072] int16
    const int* __restrict__ x,         // [64][512]
    ushort_t* __restrict__ hHI,        // [2][64][1024] bf16 hi planes
    ushort_t* __restrict__ hLO,        // [2][64][1024] bf16 lo planes
    unsigned* __restrict__ cnt,        // 4 group counters, 64 uints apart
    float* __restrict__ out)           // [64][512][1024] f32 + [64][1024] state
{
  __shared__ float part[8][3][64][4];   // [kseg][gate][lane][elem] 24KB
  const int tid  = threadIdx.x;
  const int lane = tid & 63;
  const int w    = tid >> 6;            // wave id = K-segment
  const int bx   = (int)blockIdx.x;
  const int uj   = bx & 63, bi = bx >> 6;
  const int u0   = uj * 16, b0 = bi * 16;
  const int c16  = lane & 15;           // fragment row/col-within-tile
  const int kg   = lane >> 4;           // k-group (x8)
  unsigned* mycnt = cnt + bi * 64;      // 256B apart

  // ---- Wh fragments resident in registers (built once, cached loads) ----
  // B[ks][g]: col = u0 + c16 of gate g, k = w*128 + ks*32 + kg*8 + j.
  bf16x8 BH[4][3], BL[4][3];
#pragma unroll
  for (int ks = 0; ks < 4; ++ks)
#pragma unroll
    for (int g = 0; g < 3; ++g) {
      bf16x8 bh, bl;
#pragma unroll
      for (int j = 0; j < 8; ++j) {
        int k = w * 128 + ks * 32 + kg * 8 + j;
        float v = Wh[(size_t)k * G3 + g * 1024 + u0 + c16];
        ushort_t hi = f2bf(v);
        bh[j] = (short)hi;
        bl[j] = (short)f2bf(v - bf2f(hi));
      }
      BH[ks][g] = bh;
      BL[ks][g] = bl;
    }

  // ---- epilogue ownership: waves 0-3 (tid<256): one (b,u) per thread ----
  const bool epi = (tid < 256);
  const int ebl = (tid >> 4) & 15, eul = tid & 15;
  const int eb = b0 + ebl, eu = u0 + eul;
  float brz = 0.f, brr = 0.f, brh = 0.f, hp = 0.f;
  if (epi) {
    brz = b_r[eu]; brr = b_r[1024 + eu]; brh = b_r[2048 + eu];
    hp  = hidden[(size_t)eb * U_DIM + eu];
  }

  // drain everything before entering the counted-vmcnt regime
  asm volatile("s_waitcnt vmcnt(0) lgkmcnt(0)" ::: "memory");

  // prologue: prefetch xq for t=0 (whole waves are epi or not -> per-wave
  // vmcnt discipline stays uniform; epi waves carry 4 extra in-flight loads,
  // and every WAITV count below is correct for both cases).
  int xq0 = 0, xq1 = 0, xq2 = 0, xtok = 0;
  if (epi) {
    xq0 = ldg_sshort(xp + (size_t)eb * G3 + eu);
    xq1 = ldg_sshort(xp + (size_t)eb * G3 + 1024 + eu);
    xq2 = ldg_sshort(xp + (size_t)eb * G3 + 2048 + eu);
    xtok = ldg_s32(x + eb * T_LEN + 0);
  }

  unsigned target = 0;
  unsigned spins = 0;            // global spin budget: deadlock bails visibly
  for (int t = 0; t < T_LEN; ++t) {
    const ushort_t* __restrict__ rH = hHI + (size_t)(t & 1) * BU;
    const ushort_t* __restrict__ rL = hLO + (size_t)(t & 1) * BU;
    ushort_t* __restrict__ wrH = hHI + (size_t)((t + 1) & 1) * BU;
    ushort_t* __restrict__ wrL = hLO + (size_t)((t + 1) & 1) * BU;

    // A rows = this group's 16 h-rows; row c16, k-base w*128 + kg*8
    const ushort_t* pH = rH + (size_t)(b0 + c16) * U_DIM + w * 128 + kg * 8;
    const ushort_t* pL = rL + (size_t)(b0 + c16) * U_DIM + w * 128 + kg * 8;

    f32x4 acc[3];
#pragma unroll
    for (int g = 0; g < 3; ++g) acc[g] = (f32x4){0.f, 0.f, 0.f, 0.f};

    // issue all 8 A-loads upfront; vmem order per epi-wave:
    //   [4 xq] A0H A0L A1H A1L A2H A2L A3H A3L
    //   WAITV(6): xq+A0 done | WAITV(4): A1 | WAITV(2): A2 | WAITV(0): A3.
    // non-epi waves have the same 8 A-loads with 0 xq: counts still correct.
    bf16x8 AH0, AL0, AH1, AL1, AH2, AL2, AH3, AL3;
    AH0 = ldg_cohere_b128(pH + 0 * 32);  AL0 = ldg_cohere_b128(pL + 0 * 32);
    AH1 = ldg_cohere_b128(pH + 1 * 32);  AL1 = ldg_cohere_b128(pL + 1 * 32);
    AH2 = ldg_cohere_b128(pH + 2 * 32);  AL2 = ldg_cohere_b128(pL + 2 * 32);
    AH3 = ldg_cohere_b128(pH + 3 * 32);  AL3 = ldg_cohere_b128(pL + 3 * 32);

#define COMP(AH_, AL_, ks_) \
    _Pragma("unroll") \
    for (int g = 0; g < 3; ++g) { \
      acc[g] = __builtin_amdgcn_mfma_f32_16x16x32_bf16(AH_, BH[ks_][g], acc[g], 0, 0, 0); \
      acc[g] = __builtin_amdgcn_mfma_f32_16x16x32_bf16(AH_, BL[ks_][g], acc[g], 0, 0, 0); \
      acc[g] = __builtin_amdgcn_mfma_f32_16x16x32_bf16(AL_, BH[ks_][g], acc[g], 0, 0, 0); \
    }
    WAITV(6);
    COMP(AH0, AL0, 0)
    WAITV(4);
    COMP(AH1, AL1, 1)
    WAITV(2);
    COMP(AH2, AL2, 2)
    WAITV(0);
    COMP(AH3, AL3, 3)
#undef COMP

    // ---- K-segment partials -> LDS, lane-major: contiguous b128 writes ----
#pragma unroll
    for (int g = 0; g < 3; ++g)
      *(f32x4*)&part[w][g][lane][0] = acc[g];

    __syncthreads();

    if (epi) {
      // C elem: row ebl col eul -> producer lane (ebl>>2)*16+eul, elem ebl&3
      const int pl = (ebl >> 2) * 16 + eul, pe = ebl & 3;
      float sz = 0.f, sr = 0.f, sh = 0.f;
#pragma unroll
      for (int s = 0; s < 8; ++s) {
        sz += part[s][0][pl][pe];
        sr += part[s][1][pl][pe];
        sh += part[s][2][pl][pe];
      }

      // ---- fused gate epilogue (xq values prefetched last iteration) ----
      const float hz = sz + brz, hr = sr + brr, hhv = sh + brh;
      const float xz = (float)xq0 * XP_INV;
      const float xr = (float)xq1 * XP_INV;
      const float xh = (float)xq2 * XP_INV;
      const float z = 1.f / (1.f + __expf(-(xz + hz)));
      const float r = 1.f / (1.f + __expf(-(xr + hr)));
      const float ca = xh + r * hhv;
      const float cand = 1.f - 2.f / (__expf(2.f * ca) + 1.f);   // tanh
      float hn = z * hp + (1.f - z) * cand;
      hn = (xtok != 0) ? hn : hp;
      hp = hn;

      out[((size_t)eb * T_LEN + t) * U_DIM + eu] = hn;      // plain store
      const ushort_t hi = f2bf(hn);
      const ushort_t lo = f2bf(hn - bf2f(hi));
      stg_cohere_u16(wrH + (size_t)eb * U_DIM + eu, (unsigned)hi);
      stg_cohere_u16(wrL + (size_t)eb * U_DIM + eu, (unsigned)lo);

      // prefetch next step's xq/x (4 outstanding across the barrier)
      const int tp = (t < T_LEN - 1) ? t + 1 : t;
      xq0 = ldg_sshort(xp + ((size_t)tp * B_SZ + eb) * G3 + eu);
      xq1 = ldg_sshort(xp + ((size_t)tp * B_SZ + eb) * G3 + 1024 + eu);
      xq2 = ldg_sshort(xp + ((size_t)tp * B_SZ + eb) * G3 + 2048 + eu);
      xtok = ldg_s32(x + eb * T_LEN + tp);
      WAITV(4);   // 3 stores drained (h visible at MALL); xq still flying
    }

    // ---- per-group grid barrier (fence-free, r8-proven protocol) ----
    target += GRPWG;
    __syncthreads();
    if (tid == 0)
      __hip_atomic_fetch_add(mycnt, 1u, __ATOMIC_RELAXED, __HIP_MEMORY_SCOPE_AGENT);
    if (w == 0) {
      while (spins < (1u << 22)) {
        if (ldg_cohere_u32(mycnt) >= target) break;
        __builtin_amdgcn_s_sleep(2);
        ++spins;
      }
    }
    __syncthreads();
    __builtin_amdgcn_sched_barrier(0);
  }

  // final state = hp (exact register carry)
  if (epi)
    out[(size_t)B_SZ * T_LEN * U_DIM + (size_t)eb * U_DIM + eu] = hp;
}

// ---------------- launch
extern "C" void kernel_launch(void* const* d_in, const int* in_sizes, int n_in,
                              void* d_out, int out_size, void* d_ws, size_t ws_size,
                              hipStream_t stream) {
  const int*   x      = (const int*)  d_in[0];
  const float* hidden = (const float*)d_in[1];
  const float* emb    = (const float*)d_in[2];
  const float* Wx     = (const float*)d_in[3];
  const float* Wh     = (const float*)d_in[4];
  const float* b_i    = (const float*)d_in[5];
  const float* b_r    = (const float*)d_in[6];
  float* out = (float*)d_out;

  const size_t XP_B = (size_t)T_LEN * B_SZ * G3 * 2;   // 201,326,592 (int16)
  const size_t NEED = XP_B + 8 * (size_t)BU + 1024;    // + h planes + counters
  if (ws_size < NEED) return;

  short*    xp  = (short*)d_ws;
  ushort_t* hHI = (ushort_t*)((char*)d_ws + XP_B);     // [2][BU] bf16-hi
  ushort_t* hLO = hHI + 2 * (size_t)BU;                // [2][BU] bf16-lo
  unsigned* cnt = (unsigned*)(hLO + 2 * (size_t)BU);   // 4 counters, 256B apart

  init_h<<<BU / 256, 256, 0, stream>>>(hidden, hHI, hLO, cnt);
  gemm_xp<<<(32768 / 128) * (G3 / 128), 256, 0, stream>>>(emb, Wx, x, b_i, xp);
  gru_scan<<<NWG, 512, 0, stream>>>(hidden, Wh, b_r, xp, x, hHI, hLO, cnt, out);
}